// Round 4
// baseline (280.705 us; speedup 1.0000x reference)
//
#include <hip/hip_runtime.h>

typedef __attribute__((ext_vector_type(8))) __bf16 bf16x8;
typedef __attribute__((ext_vector_type(4))) __bf16 bf16x4;
typedef __attribute__((ext_vector_type(4))) float f32x4;
typedef __attribute__((ext_vector_type(16))) float f32x16;

#define BSZ 4
#define CCH 512
#define SEQ 2048
#define NH  8
#define HD  64

__device__ __forceinline__ f32x4 mfma16(bf16x8 a, bf16x8 b, f32x4 c) {
  return __builtin_amdgcn_mfma_f32_16x16x32_bf16(a, b, c, 0, 0, 0);
}
__device__ __forceinline__ f32x16 mfma32(bf16x8 a, bf16x8 b, f32x16 c) {
  return __builtin_amdgcn_mfma_f32_32x32x16_bf16(a, b, c, 0, 0, 0);
}

__device__ __forceinline__ void gload16(const void* g, void* l) {
  __builtin_amdgcn_global_load_lds((const __attribute__((address_space(1))) void*)g,
                                   (__attribute__((address_space(3))) void*)l,
                                   16, 0, 0);
}

__device__ __forceinline__ unsigned cvtpk(float lo, float hi) {
  unsigned r;
  asm("v_cvt_pk_bf16_f32 %0, %1, %2" : "=v"(r) : "v"(lo), "v"(hi));
  return r;
}
__device__ __forceinline__ void pl32swap(unsigned& a, unsigned& b) {
  asm("v_permlane32_swap_b32 %0, %1" : "+v"(a), "+v"(b));
}

// ---------------- GroupNorm reduction ----------------
__global__ __launch_bounds__(256) void gn_partial(const float* __restrict__ x,
                                                  float* __restrict__ stats) {
  int b = blockIdx.y;
  const float4* xb = (const float4*)(x + ((size_t)b << 20) + (size_t)blockIdx.x * 16384);
  int tid = threadIdx.x;
  float s = 0.f, sq = 0.f;
#pragma unroll
  for (int i = 0; i < 16; ++i) {
    float4 v = xb[i * 256 + tid];
    s  += v.x + v.y + v.z + v.w;
    sq += v.x * v.x + v.y * v.y + v.z * v.z + v.w * v.w;
  }
#pragma unroll
  for (int o = 32; o > 0; o >>= 1) { s += __shfl_down(s, o); sq += __shfl_down(sq, o); }
  __shared__ float ls[4], lq[4];
  int w = tid >> 6;
  if ((tid & 63) == 0) { ls[w] = s; lq[w] = sq; }
  __syncthreads();
  if (tid == 0) {
    float S = ls[0] + ls[1] + ls[2] + ls[3];
    float Q = lq[0] + lq[1] + lq[2] + lq[3];
    atomicAdd(&stats[b], S);
    atomicAdd(&stats[4 + b], Q);
  }
}

__global__ void gn_final(float* stats) {
  int t = threadIdx.x;
  if (t < 4) {
    const float n = 1048576.f;
    float mean = stats[t] / n;
    float var = stats[4 + t] / n - mean * mean;
    stats[8 + t]  = mean;
    stats[12 + t] = rsqrtf(var + 1e-5f);
  }
}

// ---------------- normalize + transpose to [B*S, C] bf16 ----------------
__global__ __launch_bounds__(256) void norm_tr(const float* __restrict__ x,
                                               const float* __restrict__ gw,
                                               const float* __restrict__ gb,
                                               const float* __restrict__ stats,
                                               __bf16* __restrict__ h) {
  int s0 = blockIdx.x * 64, c0 = blockIdx.y * 64, b = blockIdx.z;
  float mean = stats[8 + b], rstd = stats[12 + b];
  const float* xb = x + ((size_t)b << 20);
  __shared__ __align__(16) __bf16 tile[64][72];
  int tid = threadIdx.x;
#pragma unroll
  for (int j = 0; j < 16; ++j) {
    int e = tid + j * 256;
    int cl = e >> 6, sl = e & 63;
    float vv = xb[(size_t)(c0 + cl) * 2048 + s0 + sl];
    float hn = (vv - mean) * rstd * gw[c0 + cl] + gb[c0 + cl];
    tile[cl][sl] = (__bf16)hn;
  }
  __syncthreads();
#pragma unroll
  for (int j = 0; j < 2; ++j) {
    int row = (tid >> 3) + j * 32;  // s-local
    int cg = tid & 7;
    bf16x8 pk;
#pragma unroll
    for (int e = 0; e < 8; ++e) pk[e] = tile[cg * 8 + e][row];
    *(bf16x8*)&h[(size_t)((b << 11) + s0 + row) * 512 + c0 + cg * 8] = pk;
  }
}

// ---------------- weights fp32 -> bf16 ----------------
__global__ __launch_bounds__(256) void wcvt(const float* __restrict__ wq, const float* __restrict__ wk,
                                            const float* __restrict__ wv, const float* __restrict__ wo,
                                            __bf16* __restrict__ out) {
  int i = blockIdx.x * 256 + threadIdx.x;  // 0..262143
  out[i]          = (__bf16)wq[i];
  out[262144 + i] = (__bf16)wk[i];
  out[524288 + i] = (__bf16)wv[i];
  out[786432 + i] = (__bf16)wo[i];
}

// ---------------- QKV GEMM: [8192,512] x [512,512]^T ----------------
__global__ __launch_bounds__(256) void gemm_qkv(const __bf16* __restrict__ A, const __bf16* __restrict__ Wb,
                                                const float* __restrict__ bq, const float* __restrict__ bk,
                                                const float* __restrict__ bvv,
                                                __bf16* __restrict__ oq, __bf16* __restrict__ ok,
                                                __bf16* __restrict__ ov) {
  __shared__ __align__(16) __bf16 As[128 * 64];
  __shared__ __align__(16) __bf16 Bs[128 * 64];
  int z = blockIdx.z;
  const __bf16* W = Wb + (size_t)z * 262144;
  const float* bias = z == 0 ? bq : (z == 1 ? bk : bvv);
  __bf16* out = z == 0 ? oq : (z == 1 ? ok : ov);
  int tid = threadIdx.x, wid = tid >> 6, l = tid & 63;
  int m0 = blockIdx.x * 128, n0 = blockIdx.y * 128;
  int wm = (wid >> 1) * 64, wn = (wid & 1) * 64;
  int l16 = l & 15, lg = l >> 4;
  f32x4 zero = {0.f, 0.f, 0.f, 0.f};
  f32x4 acc[4][4];
#pragma unroll
  for (int mt = 0; mt < 4; ++mt)
#pragma unroll
    for (int nt = 0; nt < 4; ++nt) acc[mt][nt] = zero;
  int srow = wid * 32 + (l >> 3);
  int scol = (l & 7) * 8;
  for (int k0 = 0; k0 < 512; k0 += 64) {
    __syncthreads();
#pragma unroll
    for (int t = 0; t < 4; ++t) {
      gload16(A + (size_t)(m0 + srow + t * 8) * 512 + k0 + scol, &As[(wid * 32 + t * 8) * 64]);
      gload16(W + (size_t)(n0 + srow + t * 8) * 512 + k0 + scol, &Bs[(wid * 32 + t * 8) * 64]);
    }
    __syncthreads();
#pragma unroll
    for (int kk = 0; kk < 64; kk += 32) {
      bf16x8 af[4], bfr[4];
#pragma unroll
      for (int mt = 0; mt < 4; ++mt) af[mt] = *(const bf16x8*)&As[(wm + mt * 16 + l16) * 64 + kk + lg * 8];
#pragma unroll
      for (int nt = 0; nt < 4; ++nt) bfr[nt] = *(const bf16x8*)&Bs[(wn + nt * 16 + l16) * 64 + kk + lg * 8];
#pragma unroll
      for (int mt = 0; mt < 4; ++mt)
#pragma unroll
        for (int nt = 0; nt < 4; ++nt) acc[mt][nt] = mfma16(af[mt], bfr[nt], acc[mt][nt]);
    }
  }
#pragma unroll
  for (int nt = 0; nt < 4; ++nt) {
    int col = n0 + wn + nt * 16 + l16;
    float bb = bias[col];
#pragma unroll
    for (int mt = 0; mt < 4; ++mt)
#pragma unroll
      for (int r = 0; r < 4; ++r)
        out[(size_t)(m0 + wm + mt * 16 + lg * 4 + r) * 512 + col] = (__bf16)(acc[mt][nt][r] + bb);
  }
}

// ---------------- V transpose -> V^T [B,H,D,S] ----------------
__global__ __launch_bounds__(256) void v_tr(const __bf16* __restrict__ v, __bf16* __restrict__ vt) {
  int s0 = blockIdx.x * 64, hh = blockIdx.y, b = blockIdx.z;
  __shared__ __align__(16) __bf16 tile[64][72];  // [d][s]
  int tid = threadIdx.x;
#pragma unroll
  for (int j = 0; j < 16; ++j) {
    int e = tid + j * 256;  // 0..4095
    int sl = e >> 6, dl = e & 63;
    tile[dl][sl] = v[(size_t)((b << 11) + s0 + sl) * 512 + hh * 64 + dl];
  }
  __syncthreads();
  const size_t base = (size_t)((b * 8 + hh) * 64) * 2048;
#pragma unroll
  for (int j = 0; j < 2; ++j) {
    int d = tid >> 2;             // 0..63
    int ch = (tid & 3) + j * 4;   // 0..7
    bf16x8 pk = *(const bf16x8*)&tile[d][ch * 8];
    *(bf16x8*)&vt[base + (size_t)d * 2048 + s0 + ch * 8] = pk;
  }
}

// ---------------- flash attention: 32x32 MFMA, in-register P, reg-prefetch ----------------
// Wave: 32 q-rows. KV step 32, unrolled x2 with A/B register buffers so tile t+1's
// K/V global loads are in flight during tile t's compute (latency-bound fix).
__global__ __launch_bounds__(256) void attn(const __bf16* __restrict__ q, const __bf16* __restrict__ k,
                                            const __bf16* __restrict__ vt, __bf16* __restrict__ ao) {
  const float C2 = 0.18033688011f;  // (1/8) * log2(e)
  const float THR = 8.0f;           // defer-max threshold (log2 units)
  int tid = threadIdx.x, w = tid >> 6, l = tid & 63;
  int q0w = blockIdx.x * 128 + w * 32;  // wave's q-row base within batch
  int hh = blockIdx.y, b = blockIdx.z;
  int l31 = l & 31, hi = l >> 5;

  // Q B-frags: lane holds Q[q0w+l31][hh*64 + dt*16 + hi*8 + j]
  bf16x8 qf[4];
  {
    const __bf16* qrow = q + ((size_t)((b << 11) + q0w + l31)) * 512 + hh * 64 + hi * 8;
#pragma unroll
    for (int dt = 0; dt < 4; ++dt) qf[dt] = *(const bf16x8*)&qrow[dt * 16];
  }

  const __bf16* kbase = k + ((size_t)(b << 11)) * 512 + hh * 64 + hi * 8;
  const __bf16* vtb = vt + ((size_t)((b * 8 + hh) * 64)) * 2048;

  f32x16 zero16 = {};
  f32x16 o2[2];
  o2[0] = zero16; o2[1] = zero16;
  float m_run = -3.0e38f, l_run = 0.f;

  auto LOADK = [&](bf16x8* kf, int kv0) {
    const __bf16* kr = kbase + (size_t)(kv0 + l31) * 512;
#pragma unroll
    for (int dt = 0; dt < 4; ++dt) kf[dt] = *(const bf16x8*)&kr[dt * 16];
  };
  auto LOADV = [&](bf16x8 (*vf)[2], int kv0) {
#pragma unroll
    for (int dblk = 0; dblk < 2; ++dblk) {
      const __bf16* vr = vtb + (size_t)(dblk * 32 + l31) * 2048 + kv0 + hi * 8;
      vf[dblk][0] = *(const bf16x8*)&vr[0];
      vf[dblk][1] = *(const bf16x8*)&vr[16];
    }
  };
  auto TILE = [&](const bf16x8* kfr, const bf16x8 (*va)[2]) {
    f32x16 sc = zero16;
    __builtin_amdgcn_s_setprio(1);
#pragma unroll
    for (int dt = 0; dt < 4; ++dt) sc = mfma32(kfr[dt], qf[dt], sc);
    __builtin_amdgcn_s_setprio(0);

    // --- softmax (per lane = per q-row) ---
    float t0 = fmaxf(fmaxf(sc[0], sc[1]), fmaxf(sc[2], sc[3]));
    float t1 = fmaxf(fmaxf(sc[4], sc[5]), fmaxf(sc[6], sc[7]));
    float t2 = fmaxf(fmaxf(sc[8], sc[9]), fmaxf(sc[10], sc[11]));
    float t3 = fmaxf(fmaxf(sc[12], sc[13]), fmaxf(sc[14], sc[15]));
    float tmax = fmaxf(fmaxf(t0, t1), fmaxf(t2, t3));
    tmax = fmaxf(tmax, __shfl_xor(tmax, 32));
    tmax *= C2;
    if (!__all(tmax <= m_run + THR)) {
      float mnew = fmaxf(m_run, tmax);
      float alpha = exp2f(m_run - mnew);
      m_run = mnew;
      l_run *= alpha;
#pragma unroll
      for (int dblk = 0; dblk < 2; ++dblk)
#pragma unroll
        for (int r = 0; r < 16; ++r) o2[dblk][r] *= alpha;
    }
    float rs = 0.f;
#pragma unroll
    for (int r = 0; r < 16; ++r) {
      float p = exp2f(__builtin_fmaf(sc[r], C2, -m_run));
      rs += p;
      sc[r] = p;
    }
    rs += __shfl_xor(rs, 32);
    l_run += rs;

    // --- P -> B-frags (in-register) + PV ---
#pragma unroll
    for (int t = 0; t < 2; ++t) {
      unsigned u0 = cvtpk(sc[8 * t + 0], sc[8 * t + 1]);
      unsigned u1 = cvtpk(sc[8 * t + 2], sc[8 * t + 3]);
      unsigned u2 = cvtpk(sc[8 * t + 4], sc[8 * t + 5]);
      unsigned u3 = cvtpk(sc[8 * t + 6], sc[8 * t + 7]);
      pl32swap(u0, u2);
      pl32swap(u1, u3);
      union { unsigned u[4]; bf16x8 v; } pb;
      pb.u[0] = u0; pb.u[1] = u1; pb.u[2] = u2; pb.u[3] = u3;
      __builtin_amdgcn_s_setprio(1);
#pragma unroll
      for (int dblk = 0; dblk < 2; ++dblk) o2[dblk] = mfma32(va[dblk][t], pb.v, o2[dblk]);
      __builtin_amdgcn_s_setprio(0);
    }
  };

  bf16x8 kA[4], kB[4];
  bf16x8 vA[2][2], vB[2][2];
  LOADK(kA, 0);
  LOADV(vA, 0);
  for (int kv0 = 0; kv0 < 2048; kv0 += 64) {
    LOADK(kB, kv0 + 32);
    LOADV(vB, kv0 + 32);
    TILE(kA, vA);
    if (kv0 + 64 < 2048) {
      LOADK(kA, kv0 + 64);
      LOADV(vA, kv0 + 64);
    }
    TILE(kB, vB);
  }

  // --- epilogue: normalize, transpose O^T->O via LDS, store ---
  float invl = 1.0f / l_run;
  __shared__ __align__(16) __bf16 tl[4][32 * 64];
  __bf16* T = tl[w];
  int swzq = (l31 & 7) * 8;
#pragma unroll
  for (int dblk = 0; dblk < 2; ++dblk)
#pragma unroll
    for (int g = 0; g < 4; ++g) {
      unsigned w0 = cvtpk(o2[dblk][g * 4 + 0] * invl, o2[dblk][g * 4 + 1] * invl);
      unsigned w1 = cvtpk(o2[dblk][g * 4 + 2] * invl, o2[dblk][g * 4 + 3] * invl);
      int d4 = dblk * 32 + g * 8 + hi * 4;
      uint2 pk2; pk2.x = w0; pk2.y = w1;
      *(uint2*)&T[l31 * 64 + (d4 ^ swzq)] = pk2;
    }
  // same-wave read-back (compiler inserts lgkmcnt wait)
  int qr = l >> 1, hf = l & 1;
  int swzr = (qr & 7) * 8;
  __bf16* aorow = ao + (size_t)((b << 11) + q0w + qr) * 512 + hh * 64;
#pragma unroll
  for (int m = 0; m < 2; ++m) {
    int e = hf * 32 + m * 16;
    bf16x8 v0 = *(const bf16x8*)&T[qr * 64 + ((e) ^ swzr)];
    bf16x8 v1 = *(const bf16x8*)&T[qr * 64 + ((e + 8) ^ swzr)];
    *(bf16x8*)&aorow[e] = v0;
    *(bf16x8*)&aorow[e + 8] = v1;
  }
}

// ---------------- out projection + residual + transpose to [B,C,S] ----------------
__global__ __launch_bounds__(256) void gemm_proj(const __bf16* __restrict__ A, const __bf16* __restrict__ W,
                                                 const float* __restrict__ bias,
                                                 const float* __restrict__ resid,
                                                 float* __restrict__ outp) {
  __shared__ __align__(16) union UU {
    struct SS { __bf16 a[128 * 64]; __bf16 b[128 * 64]; } s;
    float st[128 * 129];
  } u;
  int tid = threadIdx.x, wid = tid >> 6, l = tid & 63;
  int m0 = blockIdx.x * 128, n0 = blockIdx.y * 128;
  int wm = (wid >> 1) * 64, wn = (wid & 1) * 64;
  int l16 = l & 15, lg = l >> 4;
  f32x4 zero = {0.f, 0.f, 0.f, 0.f};
  f32x4 acc[4][4];
#pragma unroll
  for (int mt = 0; mt < 4; ++mt)
#pragma unroll
    for (int nt = 0; nt < 4; ++nt) acc[mt][nt] = zero;
  int srow = wid * 32 + (l >> 3);
  int scol = (l & 7) * 8;
  for (int k0 = 0; k0 < 512; k0 += 64) {
    __syncthreads();
#pragma unroll
    for (int t = 0; t < 4; ++t) {
      gload16(A + (size_t)(m0 + srow + t * 8) * 512 + k0 + scol, &u.s.a[(wid * 32 + t * 8) * 64]);
      gload16(W + (size_t)(n0 + srow + t * 8) * 512 + k0 + scol, &u.s.b[(wid * 32 + t * 8) * 64]);
    }
    __syncthreads();
#pragma unroll
    for (int kk = 0; kk < 64; kk += 32) {
      bf16x8 af[4], bfr[4];
#pragma unroll
      for (int mt = 0; mt < 4; ++mt) af[mt] = *(const bf16x8*)&u.s.a[(wm + mt * 16 + l16) * 64 + kk + lg * 8];
#pragma unroll
      for (int nt = 0; nt < 4; ++nt) bfr[nt] = *(const bf16x8*)&u.s.b[(wn + nt * 16 + l16) * 64 + kk + lg * 8];
#pragma unroll
      for (int mt = 0; mt < 4; ++mt)
#pragma unroll
        for (int nt = 0; nt < 4; ++nt) acc[mt][nt] = mfma16(af[mt], bfr[nt], acc[mt][nt]);
    }
  }
  __syncthreads();
#pragma unroll
  for (int nt = 0; nt < 4; ++nt) {
    int col = wn + nt * 16 + l16;
    float bb = bias[n0 + col];
#pragma unroll
    for (int mt = 0; mt < 4; ++mt)
#pragma unroll
      for (int r = 0; r < 4; ++r)
        u.st[(wm + mt * 16 + lg * 4 + r) * 129 + col] = acc[mt][nt][r] + bb;
  }
  __syncthreads();
  int b = m0 >> 11;
  int sbase = m0 & 2047;
  const float* rb = resid + ((size_t)b << 20);
  float* ob = outp + ((size_t)b << 20);
#pragma unroll
  for (int it = 0; it < 16; ++it) {
    int c = (tid >> 5) + it * 8;  // 0..127 local col
    int s4 = (tid & 31) * 4;      // 0..124 local row
    float4 r4 = *(const float4*)&rb[(size_t)(n0 + c) * 2048 + sbase + s4];
    float4 o4;
    o4.x = u.st[(s4 + 0) * 129 + c] + r4.x;
    o4.y = u.st[(s4 + 1) * 129 + c] + r4.y;
    o4.z = u.st[(s4 + 2) * 129 + c] + r4.z;
    o4.w = u.st[(s4 + 3) * 129 + c] + r4.w;
    *(float4*)&ob[(size_t)(n0 + c) * 2048 + sbase + s4] = o4;
  }
}

extern "C" void kernel_launch(void* const* d_in, const int* in_sizes, int n_in,
                              void* d_out, int out_size, void* d_ws, size_t ws_size,
                              hipStream_t stream) {
  const float* x   = (const float*)d_in[0];
  const float* gw  = (const float*)d_in[1];
  const float* gb  = (const float*)d_in[2];
  const float* wqf = (const float*)d_in[3];
  const float* bqf = (const float*)d_in[4];
  const float* wkf = (const float*)d_in[5];
  const float* bkf = (const float*)d_in[6];
  const float* wvf = (const float*)d_in[7];
  const float* bvf = (const float*)d_in[8];
  const float* wof = (const float*)d_in[9];
  const float* bof = (const float*)d_in[10];
  float* outp = (float*)d_out;

  char* ws = (char*)d_ws;
  float* stats = (float*)ws;
  const size_t MAT = (size_t)8192 * 512;  // elements
  __bf16* h  = (__bf16*)(ws + 256);
  __bf16* q  = h + MAT;
  __bf16* k  = q + MAT;
  __bf16* v  = k + MAT;
  __bf16* vt = v + MAT;
  __bf16* ao = vt + MAT;
  __bf16* wB = ao + MAT;  // 4 x 512*512

  hipMemsetAsync(stats, 0, 256, stream);
  gn_partial<<<dim3(64, 4), 256, 0, stream>>>(x, stats);
  gn_final<<<1, 64, 0, stream>>>(stats);
  norm_tr<<<dim3(32, 8, 4), 256, 0, stream>>>(x, gw, gb, stats, h);
  wcvt<<<1024, 256, 0, stream>>>(wqf, wkf, wvf, wof, wB);
  gemm_qkv<<<dim3(64, 4, 3), 256, 0, stream>>>(h, wB, bqf, bkf, bvf, q, k, v);
  v_tr<<<dim3(32, 8, 4), 256, 0, stream>>>(v, vt);
  attn<<<dim3(16, 8, 4), 256, 0, stream>>>(q, k, vt, ao);
  gemm_proj<<<dim3(64, 4), 256, 0, stream>>>(ao, wB + 3 * 262144, bof, x, outp);
}

// Round 5
// 225.295 us; speedup vs baseline: 1.2459x; 1.2459x over previous
//
#include <hip/hip_runtime.h>

typedef __attribute__((ext_vector_type(8))) __bf16 bf16x8;
typedef __attribute__((ext_vector_type(4))) __bf16 bf16x4;
typedef __attribute__((ext_vector_type(4))) float f32x4;
typedef __attribute__((ext_vector_type(16))) float f32x16;

#define BSZ 4
#define CCH 512
#define SEQ 2048
#define NH  8
#define HD  64

__device__ __forceinline__ f32x4 mfma16(bf16x8 a, bf16x8 b, f32x4 c) {
  return __builtin_amdgcn_mfma_f32_16x16x32_bf16(a, b, c, 0, 0, 0);
}
__device__ __forceinline__ f32x16 mfma32(bf16x8 a, bf16x8 b, f32x16 c) {
  return __builtin_amdgcn_mfma_f32_32x32x16_bf16(a, b, c, 0, 0, 0);
}

__device__ __forceinline__ void gload16(const void* g, void* l) {
  __builtin_amdgcn_global_load_lds((const __attribute__((address_space(1))) void*)g,
                                   (__attribute__((address_space(3))) void*)l,
                                   16, 0, 0);
}

__device__ __forceinline__ unsigned cvtpk(float lo, float hi) {
  unsigned r;
  asm("v_cvt_pk_bf16_f32 %0, %1, %2" : "=v"(r) : "v"(lo), "v"(hi));
  return r;
}
__device__ __forceinline__ void pl32swap(unsigned& a, unsigned& b) {
  asm("v_permlane32_swap_b32 %0, %1" : "+v"(a), "+v"(b));
}

// ---------------- GroupNorm reduction ----------------
__global__ __launch_bounds__(256) void gn_partial(const float* __restrict__ x,
                                                  float* __restrict__ stats) {
  int b = blockIdx.y;
  const float4* xb = (const float4*)(x + ((size_t)b << 20) + (size_t)blockIdx.x * 16384);
  int tid = threadIdx.x;
  float s = 0.f, sq = 0.f;
#pragma unroll
  for (int i = 0; i < 16; ++i) {
    float4 v = xb[i * 256 + tid];
    s  += v.x + v.y + v.z + v.w;
    sq += v.x * v.x + v.y * v.y + v.z * v.z + v.w * v.w;
  }
#pragma unroll
  for (int o = 32; o > 0; o >>= 1) { s += __shfl_down(s, o); sq += __shfl_down(sq, o); }
  __shared__ float ls[4], lq[4];
  int w = tid >> 6;
  if ((tid & 63) == 0) { ls[w] = s; lq[w] = sq; }
  __syncthreads();
  if (tid == 0) {
    float S = ls[0] + ls[1] + ls[2] + ls[3];
    float Q = lq[0] + lq[1] + lq[2] + lq[3];
    atomicAdd(&stats[b], S);
    atomicAdd(&stats[4 + b], Q);
  }
}

__global__ void gn_final(float* stats) {
  int t = threadIdx.x;
  if (t < 4) {
    const float n = 1048576.f;
    float mean = stats[t] / n;
    float var = stats[4 + t] / n - mean * mean;
    stats[8 + t]  = mean;
    stats[12 + t] = rsqrtf(var + 1e-5f);
  }
}

// ---------------- normalize + transpose to [B*S, C] bf16 ----------------
__global__ __launch_bounds__(256) void norm_tr(const float* __restrict__ x,
                                               const float* __restrict__ gw,
                                               const float* __restrict__ gb,
                                               const float* __restrict__ stats,
                                               __bf16* __restrict__ h) {
  int s0 = blockIdx.x * 64, c0 = blockIdx.y * 64, b = blockIdx.z;
  float mean = stats[8 + b], rstd = stats[12 + b];
  const float* xb = x + ((size_t)b << 20);
  __shared__ __align__(16) __bf16 tile[64][72];
  int tid = threadIdx.x;
#pragma unroll
  for (int j = 0; j < 16; ++j) {
    int e = tid + j * 256;
    int cl = e >> 6, sl = e & 63;
    float vv = xb[(size_t)(c0 + cl) * 2048 + s0 + sl];
    float hn = (vv - mean) * rstd * gw[c0 + cl] + gb[c0 + cl];
    tile[cl][sl] = (__bf16)hn;
  }
  __syncthreads();
#pragma unroll
  for (int j = 0; j < 2; ++j) {
    int row = (tid >> 3) + j * 32;  // s-local
    int cg = tid & 7;
    bf16x8 pk;
#pragma unroll
    for (int e = 0; e < 8; ++e) pk[e] = tile[cg * 8 + e][row];
    *(bf16x8*)&h[(size_t)((b << 11) + s0 + row) * 512 + c0 + cg * 8] = pk;
  }
}

// ---------------- weights fp32 -> bf16 ----------------
__global__ __launch_bounds__(256) void wcvt(const float* __restrict__ wq, const float* __restrict__ wk,
                                            const float* __restrict__ wv, const float* __restrict__ wo,
                                            __bf16* __restrict__ out) {
  int i = blockIdx.x * 256 + threadIdx.x;  // 0..262143
  out[i]          = (__bf16)wq[i];
  out[262144 + i] = (__bf16)wk[i];
  out[524288 + i] = (__bf16)wv[i];
  out[786432 + i] = (__bf16)wo[i];
}

// ---------------- QKV GEMM: [8192,512] x [512,512]^T ----------------
__global__ __launch_bounds__(256) void gemm_qkv(const __bf16* __restrict__ A, const __bf16* __restrict__ Wb,
                                                const float* __restrict__ bq, const float* __restrict__ bk,
                                                const float* __restrict__ bvv,
                                                __bf16* __restrict__ oq, __bf16* __restrict__ ok,
                                                __bf16* __restrict__ ov) {
  __shared__ __align__(16) __bf16 As[128 * 64];
  __shared__ __align__(16) __bf16 Bs[128 * 64];
  int z = blockIdx.z;
  const __bf16* W = Wb + (size_t)z * 262144;
  const float* bias = z == 0 ? bq : (z == 1 ? bk : bvv);
  __bf16* out = z == 0 ? oq : (z == 1 ? ok : ov);
  int tid = threadIdx.x, wid = tid >> 6, l = tid & 63;
  int m0 = blockIdx.x * 128, n0 = blockIdx.y * 128;
  int wm = (wid >> 1) * 64, wn = (wid & 1) * 64;
  int l16 = l & 15, lg = l >> 4;
  f32x4 zero = {0.f, 0.f, 0.f, 0.f};
  f32x4 acc[4][4];
#pragma unroll
  for (int mt = 0; mt < 4; ++mt)
#pragma unroll
    for (int nt = 0; nt < 4; ++nt) acc[mt][nt] = zero;
  int srow = wid * 32 + (l >> 3);
  int scol = (l & 7) * 8;
  for (int k0 = 0; k0 < 512; k0 += 64) {
    __syncthreads();
#pragma unroll
    for (int t = 0; t < 4; ++t) {
      gload16(A + (size_t)(m0 + srow + t * 8) * 512 + k0 + scol, &As[(wid * 32 + t * 8) * 64]);
      gload16(W + (size_t)(n0 + srow + t * 8) * 512 + k0 + scol, &Bs[(wid * 32 + t * 8) * 64]);
    }
    __syncthreads();
#pragma unroll
    for (int kk = 0; kk < 64; kk += 32) {
      bf16x8 af[4], bfr[4];
#pragma unroll
      for (int mt = 0; mt < 4; ++mt) af[mt] = *(const bf16x8*)&As[(wm + mt * 16 + l16) * 64 + kk + lg * 8];
#pragma unroll
      for (int nt = 0; nt < 4; ++nt) bfr[nt] = *(const bf16x8*)&Bs[(wn + nt * 16 + l16) * 64 + kk + lg * 8];
#pragma unroll
      for (int mt = 0; mt < 4; ++mt)
#pragma unroll
        for (int nt = 0; nt < 4; ++nt) acc[mt][nt] = mfma16(af[mt], bfr[nt], acc[mt][nt]);
    }
  }
#pragma unroll
  for (int nt = 0; nt < 4; ++nt) {
    int col = n0 + wn + nt * 16 + l16;
    float bb = bias[col];
#pragma unroll
    for (int mt = 0; mt < 4; ++mt)
#pragma unroll
      for (int r = 0; r < 4; ++r)
        out[(size_t)(m0 + wm + mt * 16 + lg * 4 + r) * 512 + col] = (__bf16)(acc[mt][nt][r] + bb);
  }
}

// ---------------- V transpose -> V^T [B,H,D,S] ----------------
__global__ __launch_bounds__(256) void v_tr(const __bf16* __restrict__ v, __bf16* __restrict__ vt) {
  int s0 = blockIdx.x * 64, hh = blockIdx.y, b = blockIdx.z;
  __shared__ __align__(16) __bf16 tile[64][72];  // [d][s]
  int tid = threadIdx.x;
#pragma unroll
  for (int j = 0; j < 16; ++j) {
    int e = tid + j * 256;  // 0..4095
    int sl = e >> 6, dl = e & 63;
    tile[dl][sl] = v[(size_t)((b << 11) + s0 + sl) * 512 + hh * 64 + dl];
  }
  __syncthreads();
  const size_t base = (size_t)((b * 8 + hh) * 64) * 2048;
#pragma unroll
  for (int j = 0; j < 2; ++j) {
    int d = tid >> 2;             // 0..63
    int ch = (tid & 3) + j * 4;   // 0..7
    bf16x8 pk = *(const bf16x8*)&tile[d][ch * 8];
    *(bf16x8*)&vt[base + (size_t)d * 2048 + s0 + ch * 8] = pk;
  }
}

// ---------------- flash attention: block-cooperative LDS-staged K/V ----------------
// Block = 4 waves, same (b,h); waves own q-row ranges. KV tile = 64.
// K/V staged via global_load_lds (coalesced 1KB/instr), double-buffered.
// LDS layout [64 rows][64 ch], rows 128B; slot-XOR swizzle (pre-swizzled global
// source, matching XOR on ds_read side) kills the 128B-row bank conflict.
// QK: mfma32(A=K-frag, B=Q-frag); softmax per-lane; P in-register (cvt_pk +
// permlane32_swap); PV: mfma32(A=Vt-frag, B=P-frag).
__global__ __launch_bounds__(256) void attn(const __bf16* __restrict__ q, const __bf16* __restrict__ k,
                                            const __bf16* __restrict__ vt, __bf16* __restrict__ ao) {
  const float C2 = 0.18033688011f;  // (1/8) * log2(e)
  const float THR = 8.0f;           // defer-max threshold (log2 units)
  int tid = threadIdx.x, w = tid >> 6, l = tid & 63;
  int q0w = blockIdx.x * 128 + w * 32;  // wave's q-row base within batch
  int hh = blockIdx.y, b = blockIdx.z;
  int l31 = l & 31, hi = l >> 5;

  __shared__ __align__(16) __bf16 smem[2][8192];  // per buf: K[64][64] | V[64][64]

  // Q B-frags: lane holds Q[q0w+l31][hh*64 + dt*16 + hi*8 + j]
  bf16x8 qf[4];
  {
    const __bf16* qrow = q + ((size_t)((b << 11) + q0w + l31)) * 512 + hh * 64 + hi * 8;
#pragma unroll
    for (int dt = 0; dt < 4; ++dt) qf[dt] = *(const bf16x8*)&qrow[dt * 16];
  }

  const __bf16* kbase = k + ((size_t)(b << 11)) * 512 + hh * 64;
  const __bf16* vtb = vt + ((size_t)((b * 8 + hh) * 64)) * 2048;

  f32x16 zero16 = {};
  f32x16 o2[2];
  o2[0] = zero16; o2[1] = zero16;
  float m_run = -3.0e38f, l_run = 0.f;

  int rloc = l >> 3;                       // 0..7 row within chunk
  int slotg = (l & 7) ^ rloc;              // pre-swizzled global slot
  int swz = (l31 & 7);                     // read-side XOR

  auto STAGE = [&](int buf, int kv0) {
#pragma unroll
    for (int i = 0; i < 4; ++i) {
      int c = w * 4 + i;                   // 0..15; 0-7 = K chunks, 8-15 = V chunks
      int row = (c & 7) * 8 + rloc;        // 0..63
      if (c < 8) {
        gload16(kbase + (size_t)(kv0 + row) * 512 + slotg * 8, &smem[buf][c * 512]);
      } else {
        gload16(vtb + (size_t)row * 2048 + kv0 + slotg * 8, &smem[buf][4096 + (c - 8) * 512]);
      }
    }
  };

  auto COMPUTE = [&](int buf) {
    const __bf16* Kt = &smem[buf][0];
    const __bf16* Vts = &smem[buf][4096];
    f32x16 sc[2];
#pragma unroll
    for (int kb = 0; kb < 2; ++kb) {
      sc[kb] = zero16;
      int r = kb * 32 + l31;
      __builtin_amdgcn_s_setprio(1);
#pragma unroll
      for (int dt = 0; dt < 4; ++dt) {
        bf16x8 kf = *(const bf16x8*)&Kt[r * 64 + ((dt * 2 + hi) ^ swz) * 8];
        sc[kb] = mfma32(kf, qf[dt], sc[kb]);
      }
      __builtin_amdgcn_s_setprio(0);
    }

    // --- softmax over 32 scores per lane (q = lane&31) ---
    float mx01 = -3.0e38f;
#pragma unroll
    for (int kb = 0; kb < 2; ++kb)
#pragma unroll
      for (int r = 0; r < 16; ++r) mx01 = fmaxf(mx01, sc[kb][r]);
    mx01 = fmaxf(mx01, __shfl_xor(mx01, 32));
    mx01 *= C2;
    if (!__all(mx01 <= m_run + THR)) {
      float mnew = fmaxf(m_run, mx01);
      float alpha = exp2f(m_run - mnew);
      m_run = mnew;
      l_run *= alpha;
#pragma unroll
      for (int dblk = 0; dblk < 2; ++dblk)
#pragma unroll
        for (int r = 0; r < 16; ++r) o2[dblk][r] *= alpha;
    }
    float rs = 0.f;
#pragma unroll
    for (int kb = 0; kb < 2; ++kb)
#pragma unroll
      for (int r = 0; r < 16; ++r) {
        float p = exp2f(__builtin_fmaf(sc[kb][r], C2, -m_run));
        rs += p;
        sc[kb][r] = p;
      }
    rs += __shfl_xor(rs, 32);
    l_run += rs;

    // --- P -> B-frags (in-register) + PV ---
#pragma unroll
    for (int t = 0; t < 4; ++t) {
      int kb = t >> 1, h8 = (t & 1) * 8;
      unsigned u0 = cvtpk(sc[kb][h8 + 0], sc[kb][h8 + 1]);
      unsigned u1 = cvtpk(sc[kb][h8 + 2], sc[kb][h8 + 3]);
      unsigned u2 = cvtpk(sc[kb][h8 + 4], sc[kb][h8 + 5]);
      unsigned u3 = cvtpk(sc[kb][h8 + 6], sc[kb][h8 + 7]);
      pl32swap(u0, u2);
      pl32swap(u1, u3);
      union { unsigned u[4]; bf16x8 v; } pb;
      pb.u[0] = u0; pb.u[1] = u1; pb.u[2] = u2; pb.u[3] = u3;
      __builtin_amdgcn_s_setprio(1);
#pragma unroll
      for (int dblk = 0; dblk < 2; ++dblk) {
        int r = dblk * 32 + l31;
        bf16x8 vf = *(const bf16x8*)&Vts[r * 64 + ((t * 2 + hi) ^ swz) * 8];
        o2[dblk] = mfma32(vf, pb.v, o2[dblk]);
      }
      __builtin_amdgcn_s_setprio(0);
    }
  };

  int cur = 0;
  STAGE(0, 0);
  __syncthreads();
  for (int t = 0; t < 32; ++t) {
    if (t + 1 < 32) STAGE(cur ^ 1, (t + 1) * 64);
    COMPUTE(cur);
    __syncthreads();
    cur ^= 1;
  }

  // --- epilogue: normalize, transpose O^T->O via LDS (reuse smem), store ---
  float invl = 1.0f / l_run;
  __bf16* T = &smem[0][w * 2048];
  int swzq = (l31 & 7) * 8;
#pragma unroll
  for (int dblk = 0; dblk < 2; ++dblk)
#pragma unroll
    for (int g = 0; g < 4; ++g) {
      unsigned w0 = cvtpk(o2[dblk][g * 4 + 0] * invl, o2[dblk][g * 4 + 1] * invl);
      unsigned w1 = cvtpk(o2[dblk][g * 4 + 2] * invl, o2[dblk][g * 4 + 3] * invl);
      int d4 = dblk * 32 + g * 8 + hi * 4;
      uint2 pk2; pk2.x = w0; pk2.y = w1;
      *(uint2*)&T[l31 * 64 + (d4 ^ swzq)] = pk2;
    }
  // same-wave read-back (compiler inserts lgkmcnt wait)
  int qr = l >> 1, hf = l & 1;
  int swzr = (qr & 7) * 8;
  __bf16* aorow = ao + (size_t)((b << 11) + q0w + qr) * 512 + hh * 64;
#pragma unroll
  for (int m = 0; m < 2; ++m) {
    int e = hf * 32 + m * 16;
    bf16x8 v0 = *(const bf16x8*)&T[qr * 64 + ((e) ^ swzr)];
    bf16x8 v1 = *(const bf16x8*)&T[qr * 64 + ((e + 8) ^ swzr)];
    *(bf16x8*)&aorow[e] = v0;
    *(bf16x8*)&aorow[e + 8] = v1;
  }
}

// ---------------- out projection + residual + transpose to [B,C,S] ----------------
__global__ __launch_bounds__(256) void gemm_proj(const __bf16* __restrict__ A, const __bf16* __restrict__ W,
                                                 const float* __restrict__ bias,
                                                 const float* __restrict__ resid,
                                                 float* __restrict__ outp) {
  __shared__ __align__(16) union UU {
    struct SS { __bf16 a[128 * 64]; __bf16 b[128 * 64]; } s;
    float st[128 * 129];
  } u;
  int tid = threadIdx.x, wid = tid >> 6, l = tid & 63;
  int m0 = blockIdx.x * 128, n0 = blockIdx.y * 128;
  int wm = (wid >> 1) * 64, wn = (wid & 1) * 64;
  int l16 = l & 15, lg = l >> 4;
  f32x4 zero = {0.f, 0.f, 0.f, 0.f};
  f32x4 acc[4][4];
#pragma unroll
  for (int mt = 0; mt < 4; ++mt)
#pragma unroll
    for (int nt = 0; nt < 4; ++nt) acc[mt][nt] = zero;
  int srow = wid * 32 + (l >> 3);
  int scol = (l & 7) * 8;
  for (int k0 = 0; k0 < 512; k0 += 64) {
    __syncthreads();
#pragma unroll
    for (int t = 0; t < 4; ++t) {
      gload16(A + (size_t)(m0 + srow + t * 8) * 512 + k0 + scol, &u.s.a[(wid * 32 + t * 8) * 64]);
      gload16(W + (size_t)(n0 + srow + t * 8) * 512 + k0 + scol, &u.s.b[(wid * 32 + t * 8) * 64]);
    }
    __syncthreads();
#pragma unroll
    for (int kk = 0; kk < 64; kk += 32) {
      bf16x8 af[4], bfr[4];
#pragma unroll
      for (int mt = 0; mt < 4; ++mt) af[mt] = *(const bf16x8*)&u.s.a[(wm + mt * 16 + l16) * 64 + kk + lg * 8];
#pragma unroll
      for (int nt = 0; nt < 4; ++nt) bfr[nt] = *(const bf16x8*)&u.s.b[(wn + nt * 16 + l16) * 64 + kk + lg * 8];
#pragma unroll
      for (int mt = 0; mt < 4; ++mt)
#pragma unroll
        for (int nt = 0; nt < 4; ++nt) acc[mt][nt] = mfma16(af[mt], bfr[nt], acc[mt][nt]);
    }
  }
  __syncthreads();
#pragma unroll
  for (int nt = 0; nt < 4; ++nt) {
    int col = wn + nt * 16 + l16;
    float bb = bias[n0 + col];
#pragma unroll
    for (int mt = 0; mt < 4; ++mt)
#pragma unroll
      for (int r = 0; r < 4; ++r)
        u.st[(wm + mt * 16 + lg * 4 + r) * 129 + col] = acc[mt][nt][r] + bb;
  }
  __syncthreads();
  int b = m0 >> 11;
  int sbase = m0 & 2047;
  const float* rb = resid + ((size_t)b << 20);
  float* ob = outp + ((size_t)b << 20);
#pragma unroll
  for (int it = 0; it < 16; ++it) {
    int c = (tid >> 5) + it * 8;  // 0..127 local col
    int s4 = (tid & 31) * 4;      // 0..124 local row
    float4 r4 = *(const float4*)&rb[(size_t)(n0 + c) * 2048 + sbase + s4];
    float4 o4;
    o4.x = u.st[(s4 + 0) * 129 + c] + r4.x;
    o4.y = u.st[(s4 + 1) * 129 + c] + r4.y;
    o4.z = u.st[(s4 + 2) * 129 + c] + r4.z;
    o4.w = u.st[(s4 + 3) * 129 + c] + r4.w;
    *(float4*)&ob[(size_t)(n0 + c) * 2048 + sbase + s4] = o4;
  }
}

extern "C" void kernel_launch(void* const* d_in, const int* in_sizes, int n_in,
                              void* d_out, int out_size, void* d_ws, size_t ws_size,
                              hipStream_t stream) {
  const float* x   = (const float*)d_in[0];
  const float* gw  = (const float*)d_in[1];
  const float* gb  = (const float*)d_in[2];
  const float* wqf = (const float*)d_in[3];
  const float* bqf = (const float*)d_in[4];
  const float* wkf = (const float*)d_in[5];
  const float* bkf = (const float*)d_in[6];
  const float* wvf = (const float*)d_in[7];
  const float* bvf = (const float*)d_in[8];
  const float* wof = (const float*)d_in[9];
  const float* bof = (const float*)d_in[10];
  float* outp = (float*)d_out;

  char* ws = (char*)d_ws;
  float* stats = (float*)ws;
  const size_t MAT = (size_t)8192 * 512;  // elements
  __bf16* h  = (__bf16*)(ws + 256);
  __bf16* q  = h + MAT;
  __bf16* k  = q + MAT;
  __bf16* v  = k + MAT;
  __bf16* vt = v + MAT;
  __bf16* ao = vt + MAT;
  __bf16* wB = ao + MAT;  // 4 x 512*512

  hipMemsetAsync(stats, 0, 256, stream);
  gn_partial<<<dim3(64, 4), 256, 0, stream>>>(x, stats);
  gn_final<<<1, 64, 0, stream>>>(stats);
  norm_tr<<<dim3(32, 8, 4), 256, 0, stream>>>(x, gw, gb, stats, h);
  wcvt<<<1024, 256, 0, stream>>>(wqf, wkf, wvf, wof, wB);
  gemm_qkv<<<dim3(64, 4, 3), 256, 0, stream>>>(h, wB, bqf, bkf, bvf, q, k, v);
  v_tr<<<dim3(32, 8, 4), 256, 0, stream>>>(v, vt);
  attn<<<dim3(16, 8, 4), 256, 0, stream>>>(q, k, vt, ao);
  gemm_proj<<<dim3(64, 4), 256, 0, stream>>>(ao, wB + 3 * 262144, bof, x, outp);
}

// Round 6
// 208.247 us; speedup vs baseline: 1.3479x; 1.0819x over previous
//
#include <hip/hip_runtime.h>

typedef __attribute__((ext_vector_type(8))) __bf16 bf16x8;
typedef __attribute__((ext_vector_type(4))) __bf16 bf16x4;
typedef __attribute__((ext_vector_type(4))) float f32x4;
typedef __attribute__((ext_vector_type(16))) float f32x16;

#define BSZ 4
#define CCH 512
#define SEQ 2048
#define NH  8
#define HD  64

__device__ __forceinline__ f32x4 mfma16(bf16x8 a, bf16x8 b, f32x4 c) {
  return __builtin_amdgcn_mfma_f32_16x16x32_bf16(a, b, c, 0, 0, 0);
}
__device__ __forceinline__ f32x16 mfma32(bf16x8 a, bf16x8 b, f32x16 c) {
  return __builtin_amdgcn_mfma_f32_32x32x16_bf16(a, b, c, 0, 0, 0);
}

__device__ __forceinline__ void gload16(const void* g, void* l) {
  __builtin_amdgcn_global_load_lds((const __attribute__((address_space(1))) void*)g,
                                   (__attribute__((address_space(3))) void*)l,
                                   16, 0, 0);
}

__device__ __forceinline__ unsigned cvtpk(float lo, float hi) {
  unsigned r;
  asm("v_cvt_pk_bf16_f32 %0, %1, %2" : "=v"(r) : "v"(lo), "v"(hi));
  return r;
}
__device__ __forceinline__ void pl32swap(unsigned& a, unsigned& b) {
  asm("v_permlane32_swap_b32 %0, %1" : "+v"(a), "+v"(b));
}

#define WAIT_VM(N)                                          \
  asm volatile("s_waitcnt vmcnt(" #N ")" ::: "memory");     \
  __builtin_amdgcn_sched_barrier(0);                        \
  __builtin_amdgcn_s_barrier();

// ---------------- GroupNorm reduction ----------------
__global__ __launch_bounds__(256) void gn_partial(const float* __restrict__ x,
                                                  float* __restrict__ stats) {
  int b = blockIdx.y;
  const float4* xb = (const float4*)(x + ((size_t)b << 20) + (size_t)blockIdx.x * 16384);
  int tid = threadIdx.x;
  float s = 0.f, sq = 0.f;
#pragma unroll
  for (int i = 0; i < 16; ++i) {
    float4 v = xb[i * 256 + tid];
    s  += v.x + v.y + v.z + v.w;
    sq += v.x * v.x + v.y * v.y + v.z * v.z + v.w * v.w;
  }
#pragma unroll
  for (int o = 32; o > 0; o >>= 1) { s += __shfl_down(s, o); sq += __shfl_down(sq, o); }
  __shared__ float ls[4], lq[4];
  int w = tid >> 6;
  if ((tid & 63) == 0) { ls[w] = s; lq[w] = sq; }
  __syncthreads();
  if (tid == 0) {
    float S = ls[0] + ls[1] + ls[2] + ls[3];
    float Q = lq[0] + lq[1] + lq[2] + lq[3];
    atomicAdd(&stats[b], S);
    atomicAdd(&stats[4 + b], Q);
  }
}

__global__ void gn_final(float* stats) {
  int t = threadIdx.x;
  if (t < 4) {
    const float n = 1048576.f;
    float mean = stats[t] / n;
    float var = stats[4 + t] / n - mean * mean;
    stats[8 + t]  = mean;
    stats[12 + t] = rsqrtf(var + 1e-5f);
  }
}

// ---------------- normalize + transpose to [B*S, C] bf16 ----------------
__global__ __launch_bounds__(256) void norm_tr(const float* __restrict__ x,
                                               const float* __restrict__ gw,
                                               const float* __restrict__ gb,
                                               const float* __restrict__ stats,
                                               __bf16* __restrict__ h) {
  int s0 = blockIdx.x * 64, c0 = blockIdx.y * 64, b = blockIdx.z;
  float mean = stats[8 + b], rstd = stats[12 + b];
  const float* xb = x + ((size_t)b << 20);
  __shared__ __align__(16) __bf16 tile[64][72];
  int tid = threadIdx.x;
#pragma unroll
  for (int j = 0; j < 16; ++j) {
    int e = tid + j * 256;
    int cl = e >> 6, sl = e & 63;
    float vv = xb[(size_t)(c0 + cl) * 2048 + s0 + sl];
    float hn = (vv - mean) * rstd * gw[c0 + cl] + gb[c0 + cl];
    tile[cl][sl] = (__bf16)hn;
  }
  __syncthreads();
#pragma unroll
  for (int j = 0; j < 2; ++j) {
    int row = (tid >> 3) + j * 32;  // s-local
    int cg = tid & 7;
    bf16x8 pk;
#pragma unroll
    for (int e = 0; e < 8; ++e) pk[e] = tile[cg * 8 + e][row];
    *(bf16x8*)&h[(size_t)((b << 11) + s0 + row) * 512 + c0 + cg * 8] = pk;
  }
}

// ---------------- weights fp32 -> bf16 ----------------
__global__ __launch_bounds__(256) void wcvt(const float* __restrict__ wq, const float* __restrict__ wk,
                                            const float* __restrict__ wv, const float* __restrict__ wo,
                                            __bf16* __restrict__ out) {
  int i = blockIdx.x * 256 + threadIdx.x;  // 0..262143
  out[i]          = (__bf16)wq[i];
  out[262144 + i] = (__bf16)wk[i];
  out[524288 + i] = (__bf16)wv[i];
  out[786432 + i] = (__bf16)wo[i];
}

// ---------------- QKV GEMM: [8192,512] x [512,512]^T, BK=32, 3-buf pipeline ----------------
// z==2 writes V^T [B,H,D,S] directly (v_tr fused).
__global__ __launch_bounds__(256) void gemm_qkv(const __bf16* __restrict__ A, const __bf16* __restrict__ Wb,
                                                const float* __restrict__ bq, const float* __restrict__ bk,
                                                const float* __restrict__ bvv,
                                                __bf16* __restrict__ oq, __bf16* __restrict__ ok,
                                                __bf16* __restrict__ ovt) {
  __shared__ __align__(16) __bf16 sA[3][4096];
  __shared__ __align__(16) __bf16 sB[3][4096];
  int z = blockIdx.z;
  const __bf16* W = Wb + (size_t)z * 262144;
  const float* bias = z == 0 ? bq : (z == 1 ? bk : bvv);
  int tid = threadIdx.x, wid = tid >> 6, l = tid & 63;
  int m0 = blockIdx.x * 128, n0 = blockIdx.y * 128;
  int wm = (wid >> 1) * 64, wn = (wid & 1) * 64;
  int l16 = l & 15, lg = l >> 4;
  f32x4 zero = {0.f, 0.f, 0.f, 0.f};
  f32x4 acc[4][4];
#pragma unroll
  for (int mt = 0; mt < 4; ++mt)
#pragma unroll
    for (int nt = 0; nt < 4; ++nt) acc[mt][nt] = zero;

  int srow = wid * 32 + (l >> 2);                 // row within 128-tile (plus t*16)
  int scol = ((l & 3) ^ ((l >> 3) & 3)) * 8;      // pre-swizzled global k-chunk
  int rs = (lg ^ ((l16 >> 1) & 3)) * 8;           // read-side phys slot

  auto STG = [&](int buf, int k0) {
#pragma unroll
    for (int t = 0; t < 2; ++t) {
      gload16(A + (size_t)(m0 + srow + t * 16) * 512 + k0 + scol, &sA[buf][(wid * 32 + t * 16) * 32]);
      gload16(W + (size_t)(n0 + srow + t * 16) * 512 + k0 + scol, &sB[buf][(wid * 32 + t * 16) * 32]);
    }
  };
  auto CMP = [&](int buf) {
    bf16x8 af[4], bfr[4];
#pragma unroll
    for (int mt = 0; mt < 4; ++mt) af[mt] = *(const bf16x8*)&sA[buf][(wm + mt * 16 + l16) * 32 + rs];
#pragma unroll
    for (int nt = 0; nt < 4; ++nt) bfr[nt] = *(const bf16x8*)&sB[buf][(wn + nt * 16 + l16) * 32 + rs];
    __builtin_amdgcn_s_setprio(1);
#pragma unroll
    for (int mt = 0; mt < 4; ++mt)
#pragma unroll
      for (int nt = 0; nt < 4; ++nt) acc[mt][nt] = mfma16(af[mt], bfr[nt], acc[mt][nt]);
    __builtin_amdgcn_s_setprio(0);
  };

  STG(0, 0); STG(1, 32);
  int bc = 0, sb = 2;
  for (int t = 0; t < 15; ++t) {
    WAIT_VM(4);
    if (t < 14) { STG(sb, (t + 2) * 32); sb = sb == 2 ? 0 : sb + 1; }
    CMP(bc); bc = bc == 2 ? 0 : bc + 1;
  }
  WAIT_VM(0);
  CMP(bc);

  if (z < 2) {
    __bf16* out = z == 0 ? oq : ok;
#pragma unroll
    for (int nt = 0; nt < 4; ++nt) {
      int col = n0 + wn + nt * 16 + l16;
      float bb = bias[col];
#pragma unroll
      for (int mt = 0; mt < 4; ++mt)
#pragma unroll
        for (int r = 0; r < 4; ++r)
          out[(size_t)(m0 + wm + mt * 16 + lg * 4 + r) * 512 + col] = (__bf16)(acc[mt][nt][r] + bb);
    }
  } else {
#pragma unroll
    for (int nt = 0; nt < 4; ++nt) {
      int col = n0 + wn + nt * 16 + l16;
      float bb = bias[col];
      int hd = col >> 6, dd = col & 63;
#pragma unroll
      for (int mt = 0; mt < 4; ++mt) {
        int sg = m0 + wm + mt * 16 + lg * 4;
        int bI = sg >> 11, sl = sg & 2047;
        bf16x4 pk;
#pragma unroll
        for (int r = 0; r < 4; ++r) pk[r] = (__bf16)(acc[mt][nt][r] + bb);
        *(bf16x4*)&ovt[((size_t)((bI * 8 + hd) * 64 + dd)) * 2048 + sl] = pk;
      }
    }
  }
}

// ---------------- flash attention: LDS-staged K/V, 3-buf counted-vmcnt pipeline ----------------
__global__ __launch_bounds__(256) void attn(const __bf16* __restrict__ q, const __bf16* __restrict__ k,
                                            const __bf16* __restrict__ vt, __bf16* __restrict__ ao) {
  const float C2 = 0.18033688011f;  // (1/8) * log2(e)
  const float THR = 8.0f;           // defer-max threshold (log2 units)
  int tid = threadIdx.x, w = tid >> 6, l = tid & 63;
  int q0w = blockIdx.x * 128 + w * 32;
  int hh = blockIdx.y, b = blockIdx.z;
  int l31 = l & 31, hi = l >> 5;

  __shared__ __align__(16) __bf16 smem[3][8192];  // per buf: K[64][64] | V[64][64]

  bf16x8 qf[4];
  {
    const __bf16* qrow = q + ((size_t)((b << 11) + q0w + l31)) * 512 + hh * 64 + hi * 8;
#pragma unroll
    for (int dt = 0; dt < 4; ++dt) qf[dt] = *(const bf16x8*)&qrow[dt * 16];
  }

  const __bf16* kbase = k + ((size_t)(b << 11)) * 512 + hh * 64;
  const __bf16* vtb = vt + ((size_t)((b * 8 + hh) * 64)) * 2048;

  f32x16 zero16 = {};
  f32x16 o2[2];
  o2[0] = zero16; o2[1] = zero16;
  float m_run = -3.0e38f, l_run = 0.f;

  int rloc = l >> 3;            // 0..7 row within chunk
  int slotg = (l & 7) ^ rloc;   // pre-swizzled global slot
  int swz = (l31 & 7);          // read-side XOR

  auto STAGE = [&](int buf, int kv0) {
#pragma unroll
    for (int i = 0; i < 4; ++i) {
      int c = w * 4 + i;                   // 0..15; 0-7 = K chunks, 8-15 = V chunks
      int row = (c & 7) * 8 + rloc;        // 0..63
      if (c < 8) {
        gload16(kbase + (size_t)(kv0 + row) * 512 + slotg * 8, &smem[buf][c * 512]);
      } else {
        gload16(vtb + (size_t)row * 2048 + kv0 + slotg * 8, &smem[buf][4096 + (c - 8) * 512]);
      }
    }
  };

  auto COMPUTE = [&](int buf) {
    const __bf16* Kt = &smem[buf][0];
    const __bf16* Vts = &smem[buf][4096];
    f32x16 sc[2];
#pragma unroll
    for (int kb = 0; kb < 2; ++kb) {
      sc[kb] = zero16;
      int r = kb * 32 + l31;
      __builtin_amdgcn_s_setprio(1);
#pragma unroll
      for (int dt = 0; dt < 4; ++dt) {
        bf16x8 kf = *(const bf16x8*)&Kt[r * 64 + ((dt * 2 + hi) ^ swz) * 8];
        sc[kb] = mfma32(kf, qf[dt], sc[kb]);
      }
      __builtin_amdgcn_s_setprio(0);
    }

    float mx01 = -3.0e38f;
#pragma unroll
    for (int kb = 0; kb < 2; ++kb)
#pragma unroll
      for (int r = 0; r < 16; ++r) mx01 = fmaxf(mx01, sc[kb][r]);
    mx01 = fmaxf(mx01, __shfl_xor(mx01, 32));
    mx01 *= C2;
    if (!__all(mx01 <= m_run + THR)) {
      float mnew = fmaxf(m_run, mx01);
      float alpha = exp2f(m_run - mnew);
      m_run = mnew;
      l_run *= alpha;
#pragma unroll
      for (int dblk = 0; dblk < 2; ++dblk)
#pragma unroll
        for (int r = 0; r < 16; ++r) o2[dblk][r] *= alpha;
    }
    float rsum = 0.f;
#pragma unroll
    for (int kb = 0; kb < 2; ++kb)
#pragma unroll
      for (int r = 0; r < 16; ++r) {
        float p = exp2f(__builtin_fmaf(sc[kb][r], C2, -m_run));
        rsum += p;
        sc[kb][r] = p;
      }
    rsum += __shfl_xor(rsum, 32);
    l_run += rsum;

#pragma unroll
    for (int t = 0; t < 4; ++t) {
      int kb = t >> 1, h8 = (t & 1) * 8;
      unsigned u0 = cvtpk(sc[kb][h8 + 0], sc[kb][h8 + 1]);
      unsigned u1 = cvtpk(sc[kb][h8 + 2], sc[kb][h8 + 3]);
      unsigned u2 = cvtpk(sc[kb][h8 + 4], sc[kb][h8 + 5]);
      unsigned u3 = cvtpk(sc[kb][h8 + 6], sc[kb][h8 + 7]);
      pl32swap(u0, u2);
      pl32swap(u1, u3);
      union { unsigned u[4]; bf16x8 v; } pb;
      pb.u[0] = u0; pb.u[1] = u1; pb.u[2] = u2; pb.u[3] = u3;
      __builtin_amdgcn_s_setprio(1);
#pragma unroll
      for (int dblk = 0; dblk < 2; ++dblk) {
        int r = dblk * 32 + l31;
        bf16x8 vf = *(const bf16x8*)&Vts[r * 64 + ((t * 2 + hi) ^ swz) * 8];
        o2[dblk] = mfma32(vf, pb.v, o2[dblk]);
      }
      __builtin_amdgcn_s_setprio(0);
    }
  };

  STAGE(0, 0);
  STAGE(1, 64);
  int bc = 0, sb = 2;
  for (int t = 0; t < 31; ++t) {
    WAIT_VM(4);
    if (t < 30) { STAGE(sb, (t + 2) * 64); sb = sb == 2 ? 0 : sb + 1; }
    COMPUTE(bc); bc = bc == 2 ? 0 : bc + 1;
  }
  WAIT_VM(0);
  COMPUTE(bc);

  // --- epilogue: normalize, transpose O^T->O via LDS (per-wave region), store ---
  float invl = 1.0f / l_run;
  __bf16* T = &smem[0][w * 2048];
  int swzq = (l31 & 7) * 8;
#pragma unroll
  for (int dblk = 0; dblk < 2; ++dblk)
#pragma unroll
    for (int g = 0; g < 4; ++g) {
      unsigned w0 = cvtpk(o2[dblk][g * 4 + 0] * invl, o2[dblk][g * 4 + 1] * invl);
      unsigned w1 = cvtpk(o2[dblk][g * 4 + 2] * invl, o2[dblk][g * 4 + 3] * invl);
      int d4 = dblk * 32 + g * 8 + hi * 4;
      uint2 pk2; pk2.x = w0; pk2.y = w1;
      *(uint2*)&T[l31 * 64 + (d4 ^ swzq)] = pk2;
    }
  int qr = l >> 1, hf = l & 1;
  int swzr = (qr & 7) * 8;
  __bf16* aorow = ao + (size_t)((b << 11) + q0w + qr) * 512 + hh * 64;
#pragma unroll
  for (int m = 0; m < 2; ++m) {
    int e = hf * 32 + m * 16;
    bf16x8 v0 = *(const bf16x8*)&T[qr * 64 + ((e) ^ swzr)];
    bf16x8 v1 = *(const bf16x8*)&T[qr * 64 + ((e + 8) ^ swzr)];
    *(bf16x8*)&aorow[e] = v0;
    *(bf16x8*)&aorow[e + 8] = v1;
  }
}

// ---------------- out projection + residual + transpose to [B,C,S] ----------------
__global__ __launch_bounds__(256) void gemm_proj(const __bf16* __restrict__ A, const __bf16* __restrict__ W,
                                                 const float* __restrict__ bias,
                                                 const float* __restrict__ resid,
                                                 float* __restrict__ outp) {
  __shared__ __align__(16) union UU {
    struct SS { __bf16 a[3][4096]; __bf16 b[3][4096]; } s;
    float st[128 * 129];
  } u;
  int tid = threadIdx.x, wid = tid >> 6, l = tid & 63;
  int m0 = blockIdx.x * 128, n0 = blockIdx.y * 128;
  int wm = (wid >> 1) * 64, wn = (wid & 1) * 64;
  int l16 = l & 15, lg = l >> 4;
  f32x4 zero = {0.f, 0.f, 0.f, 0.f};
  f32x4 acc[4][4];
#pragma unroll
  for (int mt = 0; mt < 4; ++mt)
#pragma unroll
    for (int nt = 0; nt < 4; ++nt) acc[mt][nt] = zero;

  int srow = wid * 32 + (l >> 2);
  int scol = ((l & 3) ^ ((l >> 3) & 3)) * 8;
  int rs = (lg ^ ((l16 >> 1) & 3)) * 8;

  auto STG = [&](int buf, int k0) {
#pragma unroll
    for (int t = 0; t < 2; ++t) {
      gload16(A + (size_t)(m0 + srow + t * 16) * 512 + k0 + scol, &u.s.a[buf][(wid * 32 + t * 16) * 32]);
      gload16(W + (size_t)(n0 + srow + t * 16) * 512 + k0 + scol, &u.s.b[buf][(wid * 32 + t * 16) * 32]);
    }
  };
  auto CMP = [&](int buf) {
    bf16x8 af[4], bfr[4];
#pragma unroll
    for (int mt = 0; mt < 4; ++mt) af[mt] = *(const bf16x8*)&u.s.a[buf][(wm + mt * 16 + l16) * 32 + rs];
#pragma unroll
    for (int nt = 0; nt < 4; ++nt) bfr[nt] = *(const bf16x8*)&u.s.b[buf][(wn + nt * 16 + l16) * 32 + rs];
    __builtin_amdgcn_s_setprio(1);
#pragma unroll
    for (int mt = 0; mt < 4; ++mt)
#pragma unroll
      for (int nt = 0; nt < 4; ++nt) acc[mt][nt] = mfma16(af[mt], bfr[nt], acc[mt][nt]);
    __builtin_amdgcn_s_setprio(0);
  };

  STG(0, 0); STG(1, 32);
  int bc = 0, sb = 2;
  for (int t = 0; t < 15; ++t) {
    WAIT_VM(4);
    if (t < 14) { STG(sb, (t + 2) * 32); sb = sb == 2 ? 0 : sb + 1; }
    CMP(bc); bc = bc == 2 ? 0 : bc + 1;
  }
  WAIT_VM(0);
  CMP(bc);

  __syncthreads();
#pragma unroll
  for (int nt = 0; nt < 4; ++nt) {
    int col = wn + nt * 16 + l16;
    float bb = bias[n0 + col];
#pragma unroll
    for (int mt = 0; mt < 4; ++mt)
#pragma unroll
      for (int r = 0; r < 4; ++r)
        u.st[(wm + mt * 16 + lg * 4 + r) * 129 + col] = acc[mt][nt][r] + bb;
  }
  __syncthreads();
  int b = m0 >> 11;
  int sbase = m0 & 2047;
  const float* rb = resid + ((size_t)b << 20);
  float* ob = outp + ((size_t)b << 20);
#pragma unroll
  for (int it = 0; it < 16; ++it) {
    int c = (tid >> 5) + it * 8;  // 0..127 local col
    int s4 = (tid & 31) * 4;      // 0..124 local row
    float4 r4 = *(const float4*)&rb[(size_t)(n0 + c) * 2048 + sbase + s4];
    float4 o4;
    o4.x = u.st[(s4 + 0) * 129 + c] + r4.x;
    o4.y = u.st[(s4 + 1) * 129 + c] + r4.y;
    o4.z = u.st[(s4 + 2) * 129 + c] + r4.z;
    o4.w = u.st[(s4 + 3) * 129 + c] + r4.w;
    *(float4*)&ob[(size_t)(n0 + c) * 2048 + sbase + s4] = o4;
  }
}

extern "C" void kernel_launch(void* const* d_in, const int* in_sizes, int n_in,
                              void* d_out, int out_size, void* d_ws, size_t ws_size,
                              hipStream_t stream) {
  const float* x   = (const float*)d_in[0];
  const float* gw  = (const float*)d_in[1];
  const float* gb  = (const float*)d_in[2];
  const float* wqf = (const float*)d_in[3];
  const float* bqf = (const float*)d_in[4];
  const float* wkf = (const float*)d_in[5];
  const float* bkf = (const float*)d_in[6];
  const float* wvf = (const float*)d_in[7];
  const float* bvf = (const float*)d_in[8];
  const float* wof = (const float*)d_in[9];
  const float* bof = (const float*)d_in[10];
  float* outp = (float*)d_out;

  char* ws = (char*)d_ws;
  float* stats = (float*)ws;
  const size_t MAT = (size_t)8192 * 512;  // elements
  __bf16* h  = (__bf16*)(ws + 256);
  __bf16* q  = h + MAT;
  __bf16* k  = q + MAT;
  __bf16* vt = k + MAT;
  __bf16* ao = vt + MAT;
  __bf16* wB = ao + MAT;  // 4 x 512*512

  hipMemsetAsync(stats, 0, 256, stream);
  gn_partial<<<dim3(64, 4), 256, 0, stream>>>(x, stats);
  gn_final<<<1, 64, 0, stream>>>(stats);
  norm_tr<<<dim3(32, 8, 4), 256, 0, stream>>>(x, gw, gb, stats, h);
  wcvt<<<1024, 256, 0, stream>>>(wqf, wkf, wvf, wof, wB);
  gemm_qkv<<<dim3(64, 4, 3), 256, 0, stream>>>(h, wB, bqf, bkf, bvf, q, k, vt);
  attn<<<dim3(16, 8, 4), 256, 0, stream>>>(q, k, vt, ao);
  gemm_proj<<<dim3(64, 4), 256, 0, stream>>>(ao, wB + 3 * 262144, bof, x, outp);
}

// Round 7
// 190.277 us; speedup vs baseline: 1.4752x; 1.0944x over previous
//
#include <hip/hip_runtime.h>

typedef __attribute__((ext_vector_type(8))) __bf16 bf16x8;
typedef __attribute__((ext_vector_type(4))) __bf16 bf16x4;
typedef __attribute__((ext_vector_type(4))) float f32x4;
typedef __attribute__((ext_vector_type(16))) float f32x16;

#define BSZ 4
#define CCH 512
#define SEQ 2048
#define NH  8
#define HD  64

__device__ __forceinline__ f32x4 mfma16(bf16x8 a, bf16x8 b, f32x4 c) {
  return __builtin_amdgcn_mfma_f32_16x16x32_bf16(a, b, c, 0, 0, 0);
}
__device__ __forceinline__ f32x16 mfma32(bf16x8 a, bf16x8 b, f32x16 c) {
  return __builtin_amdgcn_mfma_f32_32x32x16_bf16(a, b, c, 0, 0, 0);
}

__device__ __forceinline__ void gload16(const void* g, void* l) {
  __builtin_amdgcn_global_load_lds((const __attribute__((address_space(1))) void*)g,
                                   (__attribute__((address_space(3))) void*)l,
                                   16, 0, 0);
}

__device__ __forceinline__ unsigned cvtpk(float lo, float hi) {
  unsigned r;
  asm("v_cvt_pk_bf16_f32 %0, %1, %2" : "=v"(r) : "v"(lo), "v"(hi));
  return r;
}
__device__ __forceinline__ void pl32swap(unsigned& a, unsigned& b) {
  asm("v_permlane32_swap_b32 %0, %1" : "+v"(a), "+v"(b));
}

#define WAIT_VM(N)                                          \
  asm volatile("s_waitcnt vmcnt(" #N ")" ::: "memory");     \
  __builtin_amdgcn_sched_barrier(0);                        \
  __builtin_amdgcn_s_barrier();

// ---------------- GroupNorm partials (no atomics; 64 partials per batch) ----------------
__global__ __launch_bounds__(256) void gn_partial(const float* __restrict__ x,
                                                  float* __restrict__ stats) {
  int b = blockIdx.y;
  const float4* xb = (const float4*)(x + ((size_t)b << 20) + (size_t)blockIdx.x * 16384);
  int tid = threadIdx.x;
  float s = 0.f, sq = 0.f;
#pragma unroll
  for (int i = 0; i < 16; ++i) {
    float4 v = xb[i * 256 + tid];
    s  += v.x + v.y + v.z + v.w;
    sq += v.x * v.x + v.y * v.y + v.z * v.z + v.w * v.w;
  }
#pragma unroll
  for (int o = 32; o > 0; o >>= 1) { s += __shfl_down(s, o); sq += __shfl_down(sq, o); }
  __shared__ float ls[4], lq[4];
  int w = tid >> 6;
  if ((tid & 63) == 0) { ls[w] = s; lq[w] = sq; }
  __syncthreads();
  if (tid == 0) {
    stats[b * 64 + blockIdx.x]       = ls[0] + ls[1] + ls[2] + ls[3];
    stats[256 + b * 64 + blockIdx.x] = lq[0] + lq[1] + lq[2] + lq[3];
  }
}

// ---------------- normalize + transpose to [B*S, C] bf16 (gn_final fused) ----------------
__global__ __launch_bounds__(256) void norm_tr(const float* __restrict__ x,
                                               const float* __restrict__ gw,
                                               const float* __restrict__ gb,
                                               const float* __restrict__ stats,
                                               __bf16* __restrict__ h) {
  int s0 = blockIdx.x * 64, c0 = blockIdx.y * 64, b = blockIdx.z;
  float sacc = 0.f, qacc = 0.f;
  for (int i = 0; i < 64; ++i) {
    sacc += stats[b * 64 + i];
    qacc += stats[256 + b * 64 + i];
  }
  const float inv_n = 1.0f / 1048576.f;
  float mean = sacc * inv_n;
  float rstd = rsqrtf(qacc * inv_n - mean * mean + 1e-5f);
  const float* xb = x + ((size_t)b << 20);
  __shared__ __align__(16) __bf16 tile[64][72];
  int tid = threadIdx.x;
#pragma unroll
  for (int j = 0; j < 16; ++j) {
    int e = tid + j * 256;
    int cl = e >> 6, sl = e & 63;
    float vv = xb[(size_t)(c0 + cl) * 2048 + s0 + sl];
    float hn = (vv - mean) * rstd * gw[c0 + cl] + gb[c0 + cl];
    tile[cl][sl] = (__bf16)hn;
  }
  __syncthreads();
#pragma unroll
  for (int j = 0; j < 2; ++j) {
    int row = (tid >> 3) + j * 32;  // s-local
    int cg = tid & 7;
    bf16x8 pk;
#pragma unroll
    for (int e = 0; e < 8; ++e) pk[e] = tile[cg * 8 + e][row];
    *(bf16x8*)&h[(size_t)((b << 11) + s0 + row) * 512 + c0 + cg * 8] = pk;
  }
}

// ---------------- weights fp32 -> bf16 ----------------
__global__ __launch_bounds__(256) void wcvt(const float* __restrict__ wq, const float* __restrict__ wk,
                                            const float* __restrict__ wv, const float* __restrict__ wo,
                                            __bf16* __restrict__ out) {
  int i = blockIdx.x * 256 + threadIdx.x;  // 0..262143
  out[i]          = (__bf16)wq[i];
  out[262144 + i] = (__bf16)wk[i];
  out[524288 + i] = (__bf16)wv[i];
  out[786432 + i] = (__bf16)wo[i];
}

// ---------------- QKV GEMM: [8192,512] x [512,512]^T, BK=32, 3-buf pipeline ----------------
// z==2 writes V^T [B,H,D,S] via LDS transpose (coalesced stores).
__global__ __launch_bounds__(256) void gemm_qkv(const __bf16* __restrict__ A, const __bf16* __restrict__ Wb,
                                                const float* __restrict__ bq, const float* __restrict__ bk,
                                                const float* __restrict__ bvv,
                                                __bf16* __restrict__ oq, __bf16* __restrict__ ok,
                                                __bf16* __restrict__ ovt) {
  __shared__ __align__(16) union QU {
    struct SS { __bf16 a[3][4096]; __bf16 b[3][4096]; } s;
    __bf16 t[128 * 136];
  } u;
  int z = blockIdx.z;
  const __bf16* W = Wb + (size_t)z * 262144;
  const float* bias = z == 0 ? bq : (z == 1 ? bk : bvv);
  int tid = threadIdx.x, wid = tid >> 6, l = tid & 63;
  int m0 = blockIdx.x * 128, n0 = blockIdx.y * 128;
  int wm = (wid >> 1) * 64, wn = (wid & 1) * 64;
  int l16 = l & 15, lg = l >> 4;
  f32x4 zero = {0.f, 0.f, 0.f, 0.f};
  f32x4 acc[4][4];
#pragma unroll
  for (int mt = 0; mt < 4; ++mt)
#pragma unroll
    for (int nt = 0; nt < 4; ++nt) acc[mt][nt] = zero;

  int srow = wid * 32 + (l >> 2);                 // row within 128-tile (plus t*16)
  int scol = ((l & 3) ^ ((l >> 3) & 3)) * 8;      // pre-swizzled global k-chunk
  int rs = (lg ^ ((l16 >> 1) & 3)) * 8;           // read-side phys slot

  auto STG = [&](int buf, int k0) {
#pragma unroll
    for (int t = 0; t < 2; ++t) {
      gload16(A + (size_t)(m0 + srow + t * 16) * 512 + k0 + scol, &u.s.a[buf][(wid * 32 + t * 16) * 32]);
      gload16(W + (size_t)(n0 + srow + t * 16) * 512 + k0 + scol, &u.s.b[buf][(wid * 32 + t * 16) * 32]);
    }
  };
  auto CMP = [&](int buf) {
    bf16x8 af[4], bfr[4];
#pragma unroll
    for (int mt = 0; mt < 4; ++mt) af[mt] = *(const bf16x8*)&u.s.a[buf][(wm + mt * 16 + l16) * 32 + rs];
#pragma unroll
    for (int nt = 0; nt < 4; ++nt) bfr[nt] = *(const bf16x8*)&u.s.b[buf][(wn + nt * 16 + l16) * 32 + rs];
    __builtin_amdgcn_s_setprio(1);
#pragma unroll
    for (int mt = 0; mt < 4; ++mt)
#pragma unroll
      for (int nt = 0; nt < 4; ++nt) acc[mt][nt] = mfma16(af[mt], bfr[nt], acc[mt][nt]);
    __builtin_amdgcn_s_setprio(0);
  };

  STG(0, 0); STG(1, 32);
  int bc = 0, sb = 2;
  for (int t = 0; t < 15; ++t) {
    WAIT_VM(4);
    if (t < 14) { STG(sb, (t + 2) * 32); sb = sb == 2 ? 0 : sb + 1; }
    CMP(bc); bc = bc == 2 ? 0 : bc + 1;
  }
  WAIT_VM(0);
  CMP(bc);

  if (z < 2) {
    __bf16* out = z == 0 ? oq : ok;
#pragma unroll
    for (int nt = 0; nt < 4; ++nt) {
      int col = n0 + wn + nt * 16 + l16;
      float bb = bias[col];
#pragma unroll
      for (int mt = 0; mt < 4; ++mt)
#pragma unroll
        for (int r = 0; r < 4; ++r)
          out[(size_t)(m0 + wm + mt * 16 + lg * 4 + r) * 512 + col] = (__bf16)(acc[mt][nt][r] + bb);
    }
  } else {
    __syncthreads();
    // stage transposed: t[col][m], stride 136 (keeps 16B alignment for b128)
#pragma unroll
    for (int nt = 0; nt < 4; ++nt) {
      int col = wn + nt * 16 + l16;
      float bb = bias[n0 + col];
#pragma unroll
      for (int mt = 0; mt < 4; ++mt)
#pragma unroll
        for (int r = 0; r < 4; ++r)
          u.t[col * 136 + wm + mt * 16 + lg * 4 + r] = (__bf16)(acc[mt][nt][r] + bb);
    }
    __syncthreads();
    int bI = m0 >> 11, sbase = m0 & 2047;
#pragma unroll
    for (int p = 0; p < 8; ++p) {
      int row = (tid >> 4) + p * 16;     // local col of C = d index
      int ck = tid & 15;
      bf16x8 v = *(const bf16x8*)&u.t[row * 136 + ck * 8];
      int colg = n0 + row;
      int hd = colg >> 6, dd = colg & 63;
      *(bf16x8*)&ovt[((size_t)((bI * 8 + hd) * 64 + dd)) * 2048 + sbase + ck * 8] = v;
    }
  }
}

// ---------------- flash attention: LDS-staged K/V, 3-buf counted-vmcnt, MFMA row-sum ----------------
__global__ __launch_bounds__(256) void attn(const __bf16* __restrict__ q, const __bf16* __restrict__ k,
                                            const __bf16* __restrict__ vt, __bf16* __restrict__ ao) {
  const float C2 = 0.18033688011f;  // (1/8) * log2(e)
  const float THR = 8.0f;           // defer-max threshold (log2 units)
  int tid = threadIdx.x, w = tid >> 6, l = tid & 63;
  int q0w = blockIdx.x * 128 + w * 32;
  int hh = blockIdx.y, b = blockIdx.z;
  int l31 = l & 31, hi = l >> 5;

  __shared__ __align__(16) __bf16 smem[3][8192];  // per buf: K[64][64] | V[64][64]

  bf16x8 qf[4];
  {
    const __bf16* qrow = q + ((size_t)((b << 11) + q0w + l31)) * 512 + hh * 64 + hi * 8;
#pragma unroll
    for (int dt = 0; dt < 4; ++dt) qf[dt] = *(const bf16x8*)&qrow[dt * 16];
  }
  bf16x8 ones;
#pragma unroll
  for (int j = 0; j < 8; ++j) ones[j] = (__bf16)1.0f;

  const __bf16* kbase = k + ((size_t)(b << 11)) * 512 + hh * 64;
  const __bf16* vtb = vt + ((size_t)((b * 8 + hh) * 64)) * 2048;

  f32x16 zero16 = {};
  f32x16 o2[2];
  o2[0] = zero16; o2[1] = zero16;
  f32x16 facc = zero16;           // MFMA row-sum accumulator (all rows equal)
  float m_run = -3.0e38f;

  int rloc = l >> 3;              // 0..7 row within chunk
  int swz = (l31 & 7);            // read-side XOR (row&7)
  int q3 = (l31 >> 3) & 3;        // read-side XOR ((row>>3)&3)

  auto STAGE = [&](int buf, int kv0) {
#pragma unroll
    for (int i = 0; i < 4; ++i) {
      int c = w * 4 + i;                   // 0..15; 0-7 = K chunks, 8-15 = V chunks
      int cc = c & 7;
      int row = cc * 8 + rloc;             // 0..63
      int sg = (((l & 7) ^ rloc ^ (cc & 3))) * 8;
      if (c < 8) {
        gload16(kbase + (size_t)(kv0 + row) * 512 + sg, &smem[buf][c * 512]);
      } else {
        gload16(vtb + (size_t)row * 2048 + kv0 + sg, &smem[buf][4096 + cc * 512]);
      }
    }
  };

  auto COMPUTE = [&](int buf) {
    const __bf16* Kt = &smem[buf][0];
    const __bf16* Vts = &smem[buf][4096];
    f32x16 sc[2];
#pragma unroll
    for (int kb = 0; kb < 2; ++kb) {
      sc[kb] = zero16;
      int r = kb * 32 + l31;
      __builtin_amdgcn_s_setprio(1);
#pragma unroll
      for (int dt = 0; dt < 4; ++dt) {
        bf16x8 kf = *(const bf16x8*)&Kt[r * 64 + ((dt * 2 + hi) ^ swz ^ q3) * 8];
        sc[kb] = mfma32(kf, qf[dt], sc[kb]);
      }
      __builtin_amdgcn_s_setprio(0);
    }

    float mx01 = -3.0e38f;
#pragma unroll
    for (int kb = 0; kb < 2; ++kb)
#pragma unroll
      for (int r = 0; r < 16; ++r) mx01 = fmaxf(mx01, sc[kb][r]);
    mx01 = fmaxf(mx01, __shfl_xor(mx01, 32));
    mx01 *= C2;
    if (!__all(mx01 <= m_run + THR)) {
      float mnew = fmaxf(m_run, mx01);
      float alpha = exp2f(m_run - mnew);
      m_run = mnew;
#pragma unroll
      for (int r = 0; r < 16; ++r) facc[r] *= alpha;
#pragma unroll
      for (int dblk = 0; dblk < 2; ++dblk)
#pragma unroll
        for (int r = 0; r < 16; ++r) o2[dblk][r] *= alpha;
    }
#pragma unroll
    for (int kb = 0; kb < 2; ++kb)
#pragma unroll
      for (int r = 0; r < 16; ++r)
        sc[kb][r] = exp2f(__builtin_fmaf(sc[kb][r], C2, -m_run));

#pragma unroll
    for (int t = 0; t < 4; ++t) {
      int kb = t >> 1, h8 = (t & 1) * 8;
      unsigned u0 = cvtpk(sc[kb][h8 + 0], sc[kb][h8 + 1]);
      unsigned u1 = cvtpk(sc[kb][h8 + 2], sc[kb][h8 + 3]);
      unsigned u2 = cvtpk(sc[kb][h8 + 4], sc[kb][h8 + 5]);
      unsigned u3 = cvtpk(sc[kb][h8 + 6], sc[kb][h8 + 7]);
      pl32swap(u0, u2);
      pl32swap(u1, u3);
      union { unsigned u[4]; bf16x8 v; } pb;
      pb.u[0] = u0; pb.u[1] = u1; pb.u[2] = u2; pb.u[3] = u3;
      __builtin_amdgcn_s_setprio(1);
      facc = mfma32(ones, pb.v, facc);   // row-sum of P on the MFMA pipe
#pragma unroll
      for (int dblk = 0; dblk < 2; ++dblk) {
        int r = dblk * 32 + l31;
        bf16x8 vf = *(const bf16x8*)&Vts[r * 64 + ((t * 2 + hi) ^ swz ^ q3) * 8];
        o2[dblk] = mfma32(vf, pb.v, o2[dblk]);
      }
      __builtin_amdgcn_s_setprio(0);
    }
  };

  STAGE(0, 0);
  STAGE(1, 64);
  int bc = 0, sb = 2;
  for (int t = 0; t < 31; ++t) {
    WAIT_VM(4);
    if (t < 30) { STAGE(sb, (t + 2) * 64); sb = sb == 2 ? 0 : sb + 1; }
    COMPUTE(bc); bc = bc == 2 ? 0 : bc + 1;
  }
  WAIT_VM(0);
  COMPUTE(bc);

  // --- epilogue: normalize, transpose O^T->O via LDS (buf0, final compute used buf1), store ---
  float invl = 1.0f / facc[0];
  __bf16* T = &smem[0][w * 2048];
  int swzq = (l31 & 7) * 8;
#pragma unroll
  for (int dblk = 0; dblk < 2; ++dblk)
#pragma unroll
    for (int g = 0; g < 4; ++g) {
      unsigned w0 = cvtpk(o2[dblk][g * 4 + 0] * invl, o2[dblk][g * 4 + 1] * invl);
      unsigned w1 = cvtpk(o2[dblk][g * 4 + 2] * invl, o2[dblk][g * 4 + 3] * invl);
      int d4 = dblk * 32 + g * 8 + hi * 4;
      uint2 pk2; pk2.x = w0; pk2.y = w1;
      *(uint2*)&T[l31 * 64 + (d4 ^ swzq)] = pk2;
    }
  int qr = l >> 1, hf = l & 1;
  int swzr = (qr & 7) * 8;
  __bf16* aorow = ao + (size_t)((b << 11) + q0w + qr) * 512 + hh * 64;
#pragma unroll
  for (int m = 0; m < 2; ++m) {
    int e = hf * 32 + m * 16;
    bf16x8 v0 = *(const bf16x8*)&T[qr * 64 + ((e) ^ swzr)];
    bf16x8 v1 = *(const bf16x8*)&T[qr * 64 + ((e + 8) ^ swzr)];
    *(bf16x8*)&aorow[e] = v0;
    *(bf16x8*)&aorow[e + 8] = v1;
  }
}

// ---------------- out projection + residual + transpose to [B,C,S] ----------------
__global__ __launch_bounds__(256) void gemm_proj(const __bf16* __restrict__ A, const __bf16* __restrict__ W,
                                                 const float* __restrict__ bias,
                                                 const float* __restrict__ resid,
                                                 float* __restrict__ outp) {
  __shared__ __align__(16) union UU {
    struct SS { __bf16 a[3][4096]; __bf16 b[3][4096]; } s;
    float st[128 * 129];
  } u;
  int tid = threadIdx.x, wid = tid >> 6, l = tid & 63;
  int m0 = blockIdx.x * 128, n0 = blockIdx.y * 128;
  int wm = (wid >> 1) * 64, wn = (wid & 1) * 64;
  int l16 = l & 15, lg = l >> 4;
  f32x4 zero = {0.f, 0.f, 0.f, 0.f};
  f32x4 acc[4][4];
#pragma unroll
  for (int mt = 0; mt < 4; ++mt)
#pragma unroll
    for (int nt = 0; nt < 4; ++nt) acc[mt][nt] = zero;

  int srow = wid * 32 + (l >> 2);
  int scol = ((l & 3) ^ ((l >> 3) & 3)) * 8;
  int rs = (lg ^ ((l16 >> 1) & 3)) * 8;

  auto STG = [&](int buf, int k0) {
#pragma unroll
    for (int t = 0; t < 2; ++t) {
      gload16(A + (size_t)(m0 + srow + t * 16) * 512 + k0 + scol, &u.s.a[buf][(wid * 32 + t * 16) * 32]);
      gload16(W + (size_t)(n0 + srow + t * 16) * 512 + k0 + scol, &u.s.b[buf][(wid * 32 + t * 16) * 32]);
    }
  };
  auto CMP = [&](int buf) {
    bf16x8 af[4], bfr[4];
#pragma unroll
    for (int mt = 0; mt < 4; ++mt) af[mt] = *(const bf16x8*)&u.s.a[buf][(wm + mt * 16 + l16) * 32 + rs];
#pragma unroll
    for (int nt = 0; nt < 4; ++nt) bfr[nt] = *(const bf16x8*)&u.s.b[buf][(wn + nt * 16 + l16) * 32 + rs];
    __builtin_amdgcn_s_setprio(1);
#pragma unroll
    for (int mt = 0; mt < 4; ++mt)
#pragma unroll
      for (int nt = 0; nt < 4; ++nt) acc[mt][nt] = mfma16(af[mt], bfr[nt], acc[mt][nt]);
    __builtin_amdgcn_s_setprio(0);
  };

  STG(0, 0); STG(1, 32);
  int bc = 0, sb = 2;
  for (int t = 0; t < 15; ++t) {
    WAIT_VM(4);
    if (t < 14) { STG(sb, (t + 2) * 32); sb = sb == 2 ? 0 : sb + 1; }
    CMP(bc); bc = bc == 2 ? 0 : bc + 1;
  }
  WAIT_VM(0);
  CMP(bc);

  __syncthreads();
#pragma unroll
  for (int nt = 0; nt < 4; ++nt) {
    int col = wn + nt * 16 + l16;
    float bb = bias[n0 + col];
#pragma unroll
    for (int mt = 0; mt < 4; ++mt)
#pragma unroll
      for (int r = 0; r < 4; ++r)
        u.st[(wm + mt * 16 + lg * 4 + r) * 129 + col] = acc[mt][nt][r] + bb;
  }
  __syncthreads();
  int b = m0 >> 11;
  int sbase = m0 & 2047;
  const float* rb = resid + ((size_t)b << 20);
  float* ob = outp + ((size_t)b << 20);
#pragma unroll
  for (int it = 0; it < 16; ++it) {
    int c = (tid >> 5) + it * 8;  // 0..127 local col
    int s4 = (tid & 31) * 4;      // 0..124 local row
    float4 r4 = *(const float4*)&rb[(size_t)(n0 + c) * 2048 + sbase + s4];
    float4 o4;
    o4.x = u.st[(s4 + 0) * 129 + c] + r4.x;
    o4.y = u.st[(s4 + 1) * 129 + c] + r4.y;
    o4.z = u.st[(s4 + 2) * 129 + c] + r4.z;
    o4.w = u.st[(s4 + 3) * 129 + c] + r4.w;
    *(float4*)&ob[(size_t)(n0 + c) * 2048 + sbase + s4] = o4;
  }
}

extern "C" void kernel_launch(void* const* d_in, const int* in_sizes, int n_in,
                              void* d_out, int out_size, void* d_ws, size_t ws_size,
                              hipStream_t stream) {
  const float* x   = (const float*)d_in[0];
  const float* gw  = (const float*)d_in[1];
  const float* gb  = (const float*)d_in[2];
  const float* wqf = (const float*)d_in[3];
  const float* bqf = (const float*)d_in[4];
  const float* wkf = (const float*)d_in[5];
  const float* bkf = (const float*)d_in[6];
  const float* wvf = (const float*)d_in[7];
  const float* bvf = (const float*)d_in[8];
  const float* wof = (const float*)d_in[9];
  const float* bof = (const float*)d_in[10];
  float* outp = (float*)d_out;

  char* ws = (char*)d_ws;
  float* stats = (float*)ws;              // 512 floats of partials
  const size_t MAT = (size_t)8192 * 512;  // elements
  __bf16* h  = (__bf16*)(ws + 4096);
  __bf16* q  = h + MAT;
  __bf16* k  = q + MAT;
  __bf16* vt = k + MAT;
  __bf16* ao = vt + MAT;
  __bf16* wB = ao + MAT;  // 4 x 512*512

  gn_partial<<<dim3(64, 4), 256, 0, stream>>>(x, stats);
  norm_tr<<<dim3(32, 8, 4), 256, 0, stream>>>(x, gw, gb, stats, h);
  wcvt<<<1024, 256, 0, stream>>>(wqf, wkf, wvf, wof, wB);
  gemm_qkv<<<dim3(64, 4, 3), 256, 0, stream>>>(h, wB, bqf, bkf, bvf, q, k, vt);
  attn<<<dim3(16, 8, 4), 256, 0, stream>>>(q, k, vt, ao);
  gemm_proj<<<dim3(64, 4), 256, 0, stream>>>(ao, wB + 3 * 262144, bof, x, outp);
}